// Round 6
// baseline (22060.646 us; speedup 1.0000x reference)
//
#include <hip/hip_runtime.h>
#include <math.h>

#define NB 256
#define NT 4096
#define NH 128

#define DWL_OFF (NB*NT)            // 1048576
#define OUT_OFF (NB*NT + NB*2)     // 1049088

// fast transcendentals: v_exp_f32 + v_rcp_f32 (~1e-6 rel err, fine vs 2e-3 tolerance)
__device__ __forceinline__ float fexp2_(float x) { return __builtin_amdgcn_exp2f(x); }
__device__ __forceinline__ float frcp_(float x)  { return __builtin_amdgcn_rcpf(x); }
__device__ __forceinline__ float fsig_(float v)  { return frcp_(1.0f + fexp2_(v * -1.44269504f)); }
__device__ __forceinline__ float ftanh_(float v) { return 1.0f - 2.0f * frcp_(1.0f + fexp2_(v * 2.88539008f)); }

// DPP-based wave64 sum: 4 VALU-DPP steps (xor1,xor2,ror4,ror8 -> 16-lane row sums) + 2 shfl.
// dpp_ctrl must be an ICE -> template parameter.
template <int CTRL>
__device__ __forceinline__ float dppadd_(float v) {
    return v + __int_as_float(__builtin_amdgcn_update_dpp(0, __float_as_int(v), CTRL, 0xF, 0xF, true));
}
__device__ __forceinline__ float wave_sum_(float v) {
    v = dppadd_<0xB1>(v);   // quad_perm [1,0,3,2]  (xor 1)
    v = dppadd_<0x4E>(v);   // quad_perm [2,3,0,1]  (xor 2)
    v = dppadd_<0x124>(v);  // row_ror:4
    v = dppadd_<0x128>(v);  // row_ror:8  -> every lane holds its 16-lane row sum
    v += __shfl_xor(v, 16);
    v += __shfl_xor(v, 32);
    return v;
}

// 192 threads: wave0 = DNN path (2 rows/lane of dnn_w1) + xt reduce + W/output epilogue;
// waves 1-2 = GRU path, thread i owns gate rows (i, i+128, i+256) -> gates & h' thread-local.
// Big weights live in the unified VGPR+AGPR file (384 floats + working ~ 430 < 512 cap).
__launch_bounds__(192, 1)
__global__ void drnn_fused(const float* __restrict__ x,
                           const float* __restrict__ W0in,
                           const float* __restrict__ h0,
                           const float* __restrict__ dnn_w0, const float* __restrict__ dnn_b0,
                           const float* __restrict__ dnn_w1, const float* __restrict__ dnn_b1,
                           const float* __restrict__ dnn_w2, const float* __restrict__ dnn_b2,
                           const float* __restrict__ gru_w_ih, const float* __restrict__ gru_w_hh,
                           const float* __restrict__ gru_b_ih, const float* __restrict__ gru_b_hh,
                           const float* __restrict__ fc_w, const float* __restrict__ scaling,
                           float* __restrict__ out)
{
    __shared__ float xb[NT * 3];                  // 48 KB staged x[b]
    __shared__ float sh_h[NH];                    // single-buffer h (barrier-ordered)
    __shared__ float sh_a0[NH];
    __shared__ __align__(8)  float sh_xt[2];
    __shared__ __align__(16) float sh_part[4];    // dW partials: [wave1 p0,p1, wave2 p0,p1]

    const int tid  = threadIdx.x;
    const int lane = tid & 63;
    const int b    = blockIdx.x;
    const bool isD = (tid < 64);

    // ---- stage x[b] into LDS (3072 float4, coalesced) ----
    {
        const float4* src = (const float4*)(x + (size_t)b * (NT * 3));
        float4* dst = (float4*)xb;
        #pragma unroll
        for (int i = 0; i < 16; ++i) dst[tid + i * 192] = src[tid + i * 192];
    }

    // ---- big weights in registers (single overlaid array: D uses [0..256), G uses [0..384)) ----
    float wreg[384];
    // D-wave small weights
    float w00_0=0,w00_1=0,w00_2=0,w00_3=0, w01_0=0,w01_1=0,w01_2=0,w01_3=0;
    float b0a=0,b0b=0,b1a=0,b1b=0;
    float w2_0a=0,w2_0b=0,w2_1a=0,w2_1b=0,b2_0=0,b2_1=0,sc0=0,sc1=0;
    float Wr0=0, Wr1=0;
    // G-wave small weights/state
    float wihr0=0,wihr1=0,wihz0=0,wihz1=0,wihn0=0,wihn1=0;
    float bir=0,biz=0,bin_=0,bhr=0,bhz=0,bhn=0;
    float fc0=0,fc1=0,hreg=0;

    if (isD) {
        const float* r0 = dnn_w1 + (size_t)lane * NH;
        const float* r1 = dnn_w1 + (size_t)(lane + 64) * NH;
        #pragma unroll
        for (int k = 0; k < 128; k += 4) {
            float4 v0 = *(const float4*)(r0 + k);
            wreg[k] = v0.x; wreg[k+1] = v0.y; wreg[k+2] = v0.z; wreg[k+3] = v0.w;
            float4 v1 = *(const float4*)(r1 + k);
            wreg[128+k] = v1.x; wreg[128+k+1] = v1.y; wreg[128+k+2] = v1.z; wreg[128+k+3] = v1.w;
        }
        w00_0 = dnn_w0[lane*4+0]; w00_1 = dnn_w0[lane*4+1];
        w00_2 = dnn_w0[lane*4+2]; w00_3 = dnn_w0[lane*4+3];
        w01_0 = dnn_w0[(lane+64)*4+0]; w01_1 = dnn_w0[(lane+64)*4+1];
        w01_2 = dnn_w0[(lane+64)*4+2]; w01_3 = dnn_w0[(lane+64)*4+3];
        b0a = dnn_b0[lane]; b0b = dnn_b0[lane+64];
        b1a = dnn_b1[lane]; b1b = dnn_b1[lane+64];
        w2_0a = dnn_w2[lane];      w2_0b = dnn_w2[lane+64];
        w2_1a = dnn_w2[NH+lane];   w2_1b = dnn_w2[NH+lane+64];
        b2_0 = dnn_b2[0]; b2_1 = dnn_b2[1];
        sc0 = scaling[0]; sc1 = scaling[1];
        Wr0 = W0in[2*b]; Wr1 = W0in[2*b+1];
    } else {
        const int i = tid - 64;
        const float* rr = gru_w_hh + (size_t)i * NH;
        const float* rz = gru_w_hh + (size_t)(i + 128) * NH;
        const float* rn = gru_w_hh + (size_t)(i + 256) * NH;
        #pragma unroll
        for (int k = 0; k < 128; k += 4) {
            float4 vr = *(const float4*)(rr + k);
            wreg[k] = vr.x; wreg[k+1] = vr.y; wreg[k+2] = vr.z; wreg[k+3] = vr.w;
            float4 vz = *(const float4*)(rz + k);
            wreg[128+k] = vz.x; wreg[128+k+1] = vz.y; wreg[128+k+2] = vz.z; wreg[128+k+3] = vz.w;
            float4 vn = *(const float4*)(rn + k);
            wreg[256+k] = vn.x; wreg[256+k+1] = vn.y; wreg[256+k+2] = vn.z; wreg[256+k+3] = vn.w;
        }
        wihr0 = gru_w_ih[i*2+0];        wihr1 = gru_w_ih[i*2+1];
        wihz0 = gru_w_ih[(i+128)*2+0];  wihz1 = gru_w_ih[(i+128)*2+1];
        wihn0 = gru_w_ih[(i+256)*2+0];  wihn1 = gru_w_ih[(i+256)*2+1];
        bir = gru_b_ih[i]; biz = gru_b_ih[i+128]; bin_ = gru_b_ih[i+256];
        bhr = gru_b_hh[i]; bhz = gru_b_hh[i+128]; bhn = gru_b_hh[i+256];
        fc0 = fc_w[i]; fc1 = fc_w[NH + i];
        hreg = h0[(size_t)b * NH + i];
        sh_h[i] = hreg;
    }
    __syncthreads();

    for (int t = 0; t < NT; ++t) {
        float ghr = 0.f, ghz = 0.f, ghn = 0.f;   // G: carried across S1 in regs

        // ---------------- P1: wave0 {W-finalize(t-1); a0->a1->xt} || G {gh matvecs} ----------
        if (isD) {
            if (t > 0) {
                const float4 pp = *(const float4*)sh_part;      // broadcast
                const float d0 = (pp.x + pp.z) * sc0;
                const float d1 = (pp.y + pp.w) * sc1;
                Wr0 += d0; Wr1 += d1;                           // all lanes track W
                if (lane == 0) {
                    const int tp = t - 1;
                    out[(size_t)b * NT + tp] = fsig_(fmaf(Wr0, xb[tp * 3], Wr1));
                    float* op = out + OUT_OFF + ((size_t)b * NT + tp) * 2;
                    op[0] = Wr0; op[1] = Wr1;
                }
            }
            const float i2 = xb[t * 3 + 1], i3 = xb[t * 3 + 2];
            float a0a = fmaf(w00_0, Wr0, fmaf(w00_1, Wr1, fmaf(w00_2, i2, fmaf(w00_3, i3, b0a))));
            float a0b = fmaf(w01_0, Wr0, fmaf(w01_1, Wr1, fmaf(w01_2, i2, fmaf(w01_3, i3, b0b))));
            sh_a0[lane]      = fmaxf(a0a, 0.f);
            sh_a0[lane + 64] = fmaxf(a0b, 0.f);
            asm volatile("s_waitcnt lgkmcnt(0)" ::: "memory");  // same-wave LDS RAW ordering
            float acA0=0.f, acA1=0.f, acB0=0.f, acB1=0.f;
            #pragma unroll
            for (int k = 0; k < 128; k += 4) {
                const float4 v = *(const float4*)(sh_a0 + k);   // uniform addr -> broadcast
                acA0 = fmaf(wreg[k+0], v.x, acA0);     acA1 = fmaf(wreg[k+1], v.y, acA1);
                acA0 = fmaf(wreg[k+2], v.z, acA0);     acA1 = fmaf(wreg[k+3], v.w, acA1);
                acB0 = fmaf(wreg[128+k+0], v.x, acB0); acB1 = fmaf(wreg[128+k+1], v.y, acB1);
                acB0 = fmaf(wreg[128+k+2], v.z, acB0); acB1 = fmaf(wreg[128+k+3], v.w, acB1);
            }
            const float a1a = fmaxf(acA0 + acA1 + b1a, 0.f);
            const float a1b = fmaxf(acB0 + acB1 + b1b, 0.f);
            float s0 = fmaf(w2_0a, a1a, w2_0b * a1b);
            float s1 = fmaf(w2_1a, a1a, w2_1b * a1b);
            s0 = wave_sum_(s0);
            s1 = wave_sum_(s1);
            if (lane == 0) { sh_xt[0] = s0 + b2_0; sh_xt[1] = s1 + b2_1; }
        } else {
            float gr0=0.f,gr1=0.f,gz0=0.f,gz1=0.f,gn0=0.f,gn1=0.f;
            #pragma unroll
            for (int k = 0; k < 128; k += 4) {
                const float4 v = *(const float4*)(sh_h + k);    // uniform addr -> broadcast
                gr0 = fmaf(wreg[k+0], v.x, gr0);       gr1 = fmaf(wreg[k+1], v.y, gr1);
                gr0 = fmaf(wreg[k+2], v.z, gr0);       gr1 = fmaf(wreg[k+3], v.w, gr1);
                gz0 = fmaf(wreg[128+k+0], v.x, gz0);   gz1 = fmaf(wreg[128+k+1], v.y, gz1);
                gz0 = fmaf(wreg[128+k+2], v.z, gz0);   gz1 = fmaf(wreg[128+k+3], v.w, gz1);
                gn0 = fmaf(wreg[256+k+0], v.x, gn0);   gn1 = fmaf(wreg[256+k+1], v.y, gn1);
                gn0 = fmaf(wreg[256+k+2], v.z, gn0);   gn1 = fmaf(wreg[256+k+3], v.w, gn1);
            }
            ghr = gr0 + gr1 + bhr;
            ghz = gz0 + gz1 + bhz;
            ghn = gn0 + gn1 + bhn;
        }
        __syncthreads();   // S1: xt ready; all sh_h reads of this step done

        // ---------------- P2: G waves — gates, h' (thread-local), dW partials --------------
        if (!isD) {
            const float2 xt = *(const float2*)sh_xt;            // broadcast
            const float gir = fmaf(wihr0, xt.x, fmaf(wihr1, xt.y, bir));
            const float giz = fmaf(wihz0, xt.x, fmaf(wihz1, xt.y, biz));
            const float gin = fmaf(wihn0, xt.x, fmaf(wihn1, xt.y, bin_));
            const float rg = fsig_(gir + ghr);
            const float zg = fsig_(giz + ghz);
            const float ng = ftanh_(fmaf(rg, ghn, gin));
            const float hn = fmaf(zg, hreg - ng, ng);           // (1-z)*n + z*h
            hreg = hn;
            sh_h[tid - 64] = hn;
            float p0 = fc0 * hn;
            float p1 = fc1 * hn;
            p0 = wave_sum_(p0);
            p1 = wave_sum_(p1);
            if (lane == 0) {
                float2* pp = (float2*)(sh_part + ((tid >> 6) - 1) * 2);
                *pp = make_float2(p0, p1);
            }
        }
        __syncthreads();   // S2: h', dW partials ready
    }

    // ---------------- epilogue: finalize t = NT-1 ----------------
    if (isD) {
        const float4 pp = *(const float4*)sh_part;
        const float d0 = (pp.x + pp.z) * sc0;
        const float d1 = (pp.y + pp.w) * sc1;
        Wr0 += d0; Wr1 += d1;
        if (lane == 0) {
            const int tp = NT - 1;
            out[(size_t)b * NT + tp] = fsig_(fmaf(Wr0, xb[tp * 3], Wr1));
            float* op = out + OUT_OFF + ((size_t)b * NT + tp) * 2;
            op[0] = Wr0; op[1] = Wr1;
            out[DWL_OFF + 2*b + 0] = d0;
            out[DWL_OFF + 2*b + 1] = d1;
        }
    }
}

extern "C" void kernel_launch(void* const* d_in, const int* in_sizes, int n_in,
                              void* d_out, int out_size, void* d_ws, size_t ws_size,
                              hipStream_t stream) {
    (void)in_sizes; (void)n_in; (void)out_size; (void)d_ws; (void)ws_size;
    const float* x        = (const float*)d_in[0];
    const float* W0in     = (const float*)d_in[1];
    const float* h0       = (const float*)d_in[2];
    const float* dnn_w0   = (const float*)d_in[3];
    const float* dnn_b0   = (const float*)d_in[4];
    const float* dnn_w1   = (const float*)d_in[5];
    const float* dnn_b1   = (const float*)d_in[6];
    const float* dnn_w2   = (const float*)d_in[7];
    const float* dnn_b2   = (const float*)d_in[8];
    const float* gru_w_ih = (const float*)d_in[9];
    const float* gru_w_hh = (const float*)d_in[10];
    const float* gru_b_ih = (const float*)d_in[11];
    const float* gru_b_hh = (const float*)d_in[12];
    const float* fc_w     = (const float*)d_in[13];
    const float* scaling  = (const float*)d_in[14];
    float* out = (float*)d_out;

    drnn_fused<<<NB, 192, 0, stream>>>(x, W0in, h0, dnn_w0, dnn_b0, dnn_w1, dnn_b1,
                                       dnn_w2, dnn_b2, gru_w_ih, gru_w_hh, gru_b_ih,
                                       gru_b_hh, fc_w, scaling, out);
}